// Round 1
// 721.448 us; speedup vs baseline: 1.1469x; 1.1469x over previous
//
#include <hip/hip_runtime.h>
#include <cstdint>
#include <cstddef>

// ---------------------------------------------------------------------------
// Llama decoder layer, MI355X.  B=1, T=2048, D=2048, FF=8192, NH=32, NKV=8,
// HD=64.  bf16 MFMA, fp32 accumulate.
// out = h2 + mlp(h2) + x0, where h2 = rms(h1 + attn(h1)), h1 = rms(x0).
//
// Round 6: flash_attn rewritten around swapped-QK^T 32x32x16 MFMA:
//  - mfma(K,Q): C col = lane&31 = q  -> softmax stats fully lane-local
//    (15 in-lane fmax/adds + ONE shfl_xor(32) instead of 4 DS rounds x2).
//  - P kept in registers: v_cvt_pk_bf16_f32 + shfl_xor(32) assemble the PV
//    B-operand fragments directly (no LDS P round-trip, no threadfence,
//    zero LDS in the kernel).
//  - PV computed as O^T = mfma(Vt, P): alpha-rescale / 1/l lane-local.
//  - defer-max (THR=8) skips most O rescales; K prefetched one iter ahead;
//    V issued ~150 instrs before first use.
// GEMM / rmsnorm / epilogues unchanged from round 5.
// ---------------------------------------------------------------------------

typedef __attribute__((ext_vector_type(8))) short short8;   // 8 x bf16
typedef __attribute__((ext_vector_type(4))) float f32x4;
typedef __attribute__((ext_vector_type(16))) float f32x16;

typedef __attribute__((address_space(1))) const void gvoid_t;  // global
typedef __attribute__((address_space(3))) void lvoid_t;        // LDS

__device__ inline unsigned short f2b(float f) {   // fp32 -> bf16 (RNE)
  unsigned int u = __float_as_uint(f);
  u += 0x7fffu + ((u >> 16) & 1u);
  return (unsigned short)(u >> 16);
}
__device__ inline float b2f(unsigned short s) {
  return __uint_as_float((unsigned int)s << 16);
}
__device__ inline unsigned int pkbf(float lo, float hi) {  // 2xf32 -> packed bf16
  unsigned int r;
  asm("v_cvt_pk_bf16_f32 %0, %1, %2" : "=v"(r) : "v"(lo), "v"(hi));
  return r;
}

// ---------------------------------------------------------------------------
// Cast + transpose:  W fp32 [R][ldW]  ->  Wt bf16 [ldW-cols][R]
// ---------------------------------------------------------------------------
__global__ __launch_bounds__(256) void transpose_cast(
    const float* __restrict__ W, unsigned short* __restrict__ Wt,
    int R, int ldW) {
  __shared__ unsigned short s[32 * 36];
  const int r0 = blockIdx.y * 32, c0 = blockIdx.x * 32;
  const int tr = threadIdx.x >> 3, tc = (threadIdx.x & 7) << 2;
  const float4 v = *(const float4*)(W + (size_t)(r0 + tr) * ldW + c0 + tc);
  s[tr * 36 + tc + 0] = f2b(v.x);
  s[tr * 36 + tc + 1] = f2b(v.y);
  s[tr * 36 + tc + 2] = f2b(v.z);
  s[tr * 36 + tc + 3] = f2b(v.w);
  __syncthreads();
  ushort4 o;
  o.x = s[(tc + 0) * 36 + tr];
  o.y = s[(tc + 1) * 36 + tr];
  o.z = s[(tc + 2) * 36 + tr];
  o.w = s[(tc + 3) * 36 + tr];
  *(ushort4*)(Wt + (size_t)(c0 + tr) * R + r0 + tc) = o;
}

// ---------------------------------------------------------------------------
// RMSNorm (one block per row of 2048) -> bf16.
// ---------------------------------------------------------------------------
__global__ __launch_bounds__(256) void rmsnorm(
    const float* __restrict__ X, const float* __restrict__ g,
    unsigned short* __restrict__ ob) {
  const int row = blockIdx.x;
  const float* x = X + (size_t)row * 2048;
  float ss = 0.f;
  for (int i = threadIdx.x; i < 2048; i += 256) { float v = x[i]; ss += v * v; }
  for (int off = 32; off; off >>= 1) ss += __shfl_down(ss, off, 64);
  __shared__ float red[4];
  if ((threadIdx.x & 63) == 0) red[threadIdx.x >> 6] = ss;
  __syncthreads();
  const float tot = red[0] + red[1] + red[2] + red[3];
  const float r = rsqrtf(tot * (1.f / 2048.f) + 1e-5f);
  for (int i = threadIdx.x; i < 2048; i += 256)
    ob[(size_t)row * 2048 + i] = f2b(x[i] * g[i] * r);
}

// ---------------------------------------------------------------------------
// out = x0 + b2f(h2), vectorized x4.  Pre-fill for the split-K down-proj.
// ---------------------------------------------------------------------------
__global__ __launch_bounds__(256) void add_res(
    const unsigned short* __restrict__ h2, const float* __restrict__ x,
    float* __restrict__ out) {
  const int i = blockIdx.x * 256 + threadIdx.x;
  const ushort4 h = ((const ushort4*)h2)[i];
  const float4 xv = ((const float4*)x)[i];
  float4 o;
  o.x = xv.x + b2f(h.x); o.y = xv.y + b2f(h.y);
  o.z = xv.z + b2f(h.z); o.w = xv.w + b2f(h.w);
  ((float4*)out)[i] = o;
}

// ---------------------------------------------------------------------------
// GEMM: acc[M][N] (+)= A[M][K] * Bt[N][K]^T   (bf16 in, fp32 acc)
// 128x128 tile, BK=64, 4 waves, global_load_lds staging with XOR k-chunk
// swizzle.  (Unchanged from round 5.)
// ---------------------------------------------------------------------------
__global__ __launch_bounds__(256, 2) void gemm_bt(
    const unsigned short* __restrict__ A, const unsigned short* __restrict__ Bt,
    float* Cf, unsigned short* Cb,
    const unsigned short* add1b, const float* add2,
    int N, int Kfull, int Kchunk, int epi, int Tld,
    unsigned short* Cb2, unsigned short* Cb3) {
  __shared__ unsigned short As[128 * 64];
  __shared__ unsigned short Bs[128 * 64];
  const int tid = threadIdx.x;
  const int wave = tid >> 6, lane = tid & 63;
  const int quad = lane >> 4, l16 = lane & 15;
  const int m0 = blockIdx.y * 128, n0 = blockIdx.x * 128;
  const int wr = (wave >> 1) * 64, wc = (wave & 1) * 64;
  const int Ks = blockIdx.z * Kchunk, Ke = Ks + Kchunk;

  f32x4 acc[4][4] = {};

  for (int k0 = Ks; k0 < Ke; k0 += 64) {
#pragma unroll
    for (int p = 0; p < 4; ++p) {
      const int idx = p * 256 + tid;
      const int row = idx >> 3;
      const int kc = ((idx & 7) ^ (row & 7)) * 8;
      const unsigned short* gA = A + (size_t)(m0 + row) * Kfull + k0 + kc;
      const unsigned short* gB = Bt + (size_t)(n0 + row) * Kfull + k0 + kc;
      unsigned short* lA = As + (size_t)(p * 256 + wave * 64) * 8;
      unsigned short* lB = Bs + (size_t)(p * 256 + wave * 64) * 8;
      __builtin_amdgcn_global_load_lds((gvoid_t*)gA, (lvoid_t*)lA, 16, 0, 0);
      __builtin_amdgcn_global_load_lds((gvoid_t*)gB, (lvoid_t*)lB, 16, 0, 0);
    }
    __syncthreads();

#pragma unroll
    for (int ks = 0; ks < 2; ++ks) {
      short8 af[4], bf[4];
#pragma unroll
      for (int i = 0; i < 4; ++i) {
        const int row = wr + i * 16 + l16;
        af[i] = *(const short8*)(As + row * 64 +
                                 (((ks << 2) | quad) ^ (row & 7)) * 8);
      }
#pragma unroll
      for (int j = 0; j < 4; ++j) {
        const int row = wc + j * 16 + l16;
        bf[j] = *(const short8*)(Bs + row * 64 +
                                 (((ks << 2) | quad) ^ (row & 7)) * 8);
      }
#pragma unroll
      for (int i = 0; i < 4; ++i)
#pragma unroll
        for (int j = 0; j < 4; ++j)
          acc[i][j] = __builtin_amdgcn_mfma_f32_16x16x32_bf16(
              af[i], bf[j], acc[i][j], 0, 0, 0);
    }
    __syncthreads();
  }

  if (epi == 7 && n0 >= 2560) {   // transposed V store (block-uniform)
#pragma unroll
    for (int i = 0; i < 4; ++i)
#pragma unroll
      for (int j = 0; j < 4; ++j) {
        const int row = m0 + wr + i * 16 + quad * 4;
        const int col = n0 + wc + j * 16 + l16 - 2560;
        ushort4 o;
        o.x = f2b(acc[i][j][0]); o.y = f2b(acc[i][j][1]);
        o.z = f2b(acc[i][j][2]); o.w = f2b(acc[i][j][3]);
        *(ushort4*)(Cb3 + (size_t)col * Tld + row) = o;
      }
    return;
  }

#pragma unroll
  for (int i = 0; i < 4; ++i)
#pragma unroll
    for (int j = 0; j < 4; ++j) {
      const int rowb = m0 + wr + i * 16 + quad * 4;
      const int col = n0 + wc + j * 16 + l16;
      float invf = 0.f, sgn = 0.f;
      if (epi == 7) {
        const int ip = (col & 63) >> 1;
        invf = __expf(-(float)ip * 0.28782313662f); // 10000^(-ip/32)
        sgn = (col & 1) ? 1.f : -1.f;
      }
#pragma unroll
      for (int r = 0; r < 4; ++r) {
        const size_t idx = (size_t)(rowb + r) * N + col;
        const float v = acc[i][j][r];
        const float p = __shfl_xor(v, 1, 64);
        if (epi == 1) {
          Cf[idx] = v + b2f(add1b[idx]);
        } else if (epi == 3) {
          const float gt = b2f(add1b[idx]);
          Cb[idx] = f2b(gt / (1.f + __expf(-gt)) * v);
        } else if (epi == 4) {
          Cb[idx] = f2b(v);
        } else if (epi == 8) {
          atomicAdd(&Cf[idx], v);
        } else {  // 7: rope -> q or k (block-uniform region)
          float sn, cs;
          __sincosf((float)(rowb + r) * invf, &sn, &cs);
          const unsigned short o = f2b(v * cs + sgn * p * sn);
          if (col < 2048)
            Cb[(size_t)(rowb + r) * 2048 + col] = o;
          else
            Cb2[(size_t)(rowb + r) * 512 + col - 2048] = o;
        }
      }
    }
}

// ---------------------------------------------------------------------------
// Flash attention, swapped-QK^T 32x32x16.  One wave owns a 32-row q-tile and
// its full (causal) key range; waves fully independent, zero LDS, no barriers.
//
// QK^T:  S = mfma(Kfrag, Qfrag)  -> S[key][q], col q = lane&31 (lane-local q).
//        lane holds keys crow(r,hi) = (r&3) + 8*(r>>2) + 4*hi  (16 of 32).
// softmax: in-lane max/sum over 16 + one shfl_xor(32) to merge hi halves.
// PV:    O^T = mfma(Vtfrag, Pfrag) -> O^T[d][q], col q = lane&31, so the
//        alpha rescale and final 1/l are lane-local too.
// P-frag assembly (per 16-key slice): 4x v_cvt_pk_bf16_f32 + 2x shfl_xor(32).
// ---------------------------------------------------------------------------
__global__ __launch_bounds__(256) void flash_attn(
    const unsigned short* __restrict__ Qb, const unsigned short* __restrict__ Kb,
    const unsigned short* __restrict__ Vt, unsigned short* __restrict__ Y,
    int T) {
  const int tid = threadIdx.x;
  const int wave = tid >> 6, lane = tid & 63;
  const int l32 = lane & 31, hi = lane >> 5;
  const int h = blockIdx.y, kvh = h >> 2;
  // qtile index = blockIdx.x + wave*16  (interleaved so blocks are balanced)
  const int qt = (blockIdx.x + wave * 16) << 5;
  const int qrow = qt + l32;

  // Q fragments (B-operand: n = lane&31 = q, k = hi*8+i), pre-scaled by 1/8
  // (exact in bf16: power-of-2 exponent shift).
  short8 qf[4];
#pragma unroll
  for (int ds = 0; ds < 4; ++ds) {
    short8 v = *(const short8*)(Qb + (size_t)qrow * 2048 + h * 64 +
                                ds * 16 + hi * 8);
#pragma unroll
    for (int e = 0; e < 8; ++e)
      v[e] = (short)f2b(b2f((unsigned short)v[e]) * 0.125f);
    qf[ds] = v;
  }

  const unsigned short* Kp = Kb + (size_t)l32 * 512 + kvh * 64 + hi * 8;
  const unsigned short* Vp = Vt + (size_t)(kvh * 64 + l32) * T + hi * 8;

  const int niter = (qt >> 5) + 1;   // key tiles 0 .. qt (last one masked)
  float m_i = -3e38f, l_i = 0.f;
  f32x16 o0 = {}, o1 = {};           // O^T d-tiles 0..31 / 32..63

  short8 kf[4], kfn[4];
#pragma unroll
  for (int ds = 0; ds < 4; ++ds) kf[ds] = *(const short8*)(Kp + ds * 16);

  for (int it = 0; it < niter; ++it) {
    const int k0 = it << 5;
    // V fragments for this tile (used after softmax ~150 instrs below).
    short8 vf[2][2];
#pragma unroll
    for (int dt = 0; dt < 2; ++dt)
#pragma unroll
      for (int ks = 0; ks < 2; ++ks)
        vf[dt][ks] =
            *(const short8*)(Vp + (size_t)dt * 32 * T + k0 + ks * 16);
    // Prefetch next K tile (used next iteration; fully hidden).
    const int kn = (k0 + 32 < 2016) ? k0 + 32 : 2016;
#pragma unroll
    for (int ds = 0; ds < 4; ++ds)
      kfn[ds] = *(const short8*)(Kp + (size_t)kn * 512 + ds * 16);

    // S[key][q] = sum_d K*Q  (q = lane&31, keys = crow(r,hi))
    f32x16 S = {};
#pragma unroll
    for (int ds = 0; ds < 4; ++ds)
      S = __builtin_amdgcn_mfma_f32_32x32x16_bf16(kf[ds], qf[ds], S, 0, 0, 0);

    float s[16];
#pragma unroll
    for (int r = 0; r < 16; ++r) s[r] = S[r];
    if (k0 == qt) {   // diagonal tile: causal mask (only tile that needs it)
#pragma unroll
      for (int r = 0; r < 16; ++r)
        if (((r & 3) + 8 * (r >> 2) + 4 * hi) > l32) s[r] = -3e38f;
    }

    // tile max over all 32 keys: in-lane 16 + merge with partner lane (^32)
    float tmax = s[0];
#pragma unroll
    for (int r = 1; r < 16; ++r) tmax = fmaxf(tmax, s[r]);
    tmax = fmaxf(tmax, __shfl_xor(tmax, 32, 64));

    // defer-max: only rescale when the tile max exceeds running max by >8
    if (!__all(tmax <= m_i + 8.f)) {
      const float mn = fmaxf(m_i, tmax);
      const float al = __expf(m_i - mn);
#pragma unroll
      for (int r = 0; r < 16; ++r) { o0[r] *= al; o1[r] *= al; }
      l_i *= al;
      m_i = mn;
    }

    float p[16], rs = 0.f;
#pragma unroll
    for (int r = 0; r < 16; ++r) { p[r] = __expf(s[r] - m_i); rs += p[r]; }
    rs += __shfl_xor(rs, 32, 64);
    l_i += rs;

    // Pack P -> PV B-operand fragments, 2 slices of 16 keys.
    // Slice ks keys 16ks+0..15; lane needs keys 16ks+8hi+0..7.
    // Own regs supply half; partner (lane^32) supplies the other half.
    short8 pf[2];
#pragma unroll
    for (int ks = 0; ks < 2; ++ks) {
      const int rb = ks * 8;
      const unsigned int a0 = pkbf(p[rb + 0], p[rb + 1]);  // keys 16ks+4hi+0,1
      const unsigned int a1 = pkbf(p[rb + 2], p[rb + 3]);  // keys 16ks+4hi+2,3
      const unsigned int b0 = pkbf(p[rb + 4], p[rb + 5]);  // keys 16ks+8+4hi+0,1
      const unsigned int b1 = pkbf(p[rb + 6], p[rb + 7]);  // keys 16ks+8+4hi+2,3
      const unsigned int t0 = __shfl_xor((int)(hi ? a0 : b0), 32, 64);
      const unsigned int t1 = __shfl_xor((int)(hi ? a1 : b1), 32, 64);
      union { unsigned int u[4]; short8 v; } pu;
      pu.u[0] = hi ? t0 : a0;
      pu.u[1] = hi ? t1 : a1;
      pu.u[2] = hi ? b0 : t0;
      pu.u[3] = hi ? b1 : t1;
      pf[ks] = pu.v;
    }

    // O^T += Vt * P   (A = Vt[d][k], B = P[k][q])
#pragma unroll
    for (int ks = 0; ks < 2; ++ks) {
      o0 = __builtin_amdgcn_mfma_f32_32x32x16_bf16(vf[0][ks], pf[ks], o0,
                                                   0, 0, 0);
      o1 = __builtin_amdgcn_mfma_f32_32x32x16_bf16(vf[1][ks], pf[ks], o1,
                                                   0, 0, 0);
    }
#pragma unroll
    for (int ds = 0; ds < 4; ++ds) kf[ds] = kfn[ds];
  }

  // Epilogue: O[q][d] = O^T / l.  Lane q = lane&31; d = dt*32 + 8g + 4hi + j.
  const float inv = 1.f / l_i;
  unsigned short* Yp = Y + (size_t)qrow * 2048 + h * 64 + hi * 4;
#pragma unroll
  for (int g = 0; g < 4; ++g) {
    ushort4 u0, u1;
    u0.x = f2b(o0[g * 4 + 0] * inv); u0.y = f2b(o0[g * 4 + 1] * inv);
    u0.z = f2b(o0[g * 4 + 2] * inv); u0.w = f2b(o0[g * 4 + 3] * inv);
    *(ushort4*)(Yp + g * 8) = u0;
    u1.x = f2b(o1[g * 4 + 0] * inv); u1.y = f2b(o1[g * 4 + 1] * inv);
    u1.z = f2b(o1[g * 4 + 2] * inv); u1.w = f2b(o1[g * 4 + 3] * inv);
    *(ushort4*)(Yp + 32 + g * 8) = u1;
  }
}

// ---------------------------------------------------------------------------
extern "C" void kernel_launch(void* const* d_in, const int* in_sizes, int n_in,
                              void* d_out, int out_size, void* d_ws,
                              size_t ws_size, hipStream_t stream) {
  const float* x  = (const float*)d_in[0];
  const float* g1 = (const float*)d_in[1];
  const float* wq = (const float*)d_in[2];
  const float* wk = (const float*)d_in[3];
  const float* wv = (const float*)d_in[4];
  const float* wo = (const float*)d_in[5];
  const float* g2 = (const float*)d_in[6];
  const float* wg = (const float*)d_in[7];
  const float* wu = (const float*)d_in[8];
  const float* wd = (const float*)d_in[9];
  float* out = (float*)d_out;

  const int T = 2048, Dm = 2048, FF = 8192;
  char* ws = (char*)d_ws;
  const size_t MB = (size_t)1 << 20;

  unsigned short* wq_t = (unsigned short*)(ws + 0 * MB);    // 8 MB  } contig
  unsigned short* wk_t = (unsigned short*)(ws + 8 * MB);    // 2 MB  } rows
  unsigned short* wv_t = (unsigned short*)(ws + 10 * MB);   // 2 MB  } 0..3071
  unsigned short* wo_t = (unsigned short*)(ws + 12 * MB);   // 8 MB
  unsigned short* wg_t = (unsigned short*)(ws + 20 * MB);   // 32 MB
  unsigned short* wu_t = (unsigned short*)(ws + 52 * MB);   // 32 MB
  unsigned short* h1_b = (unsigned short*)(ws + 84 * MB);   // 8 MB
  unsigned short* h2_b = (unsigned short*)(ws + 92 * MB);   // 8 MB
  float*          x2_f = (float*)(ws + 100 * MB);           // 16 MB (dies early)
  unsigned short* gate = (unsigned short*)(ws + 100 * MB);  // 32 MB (in-place)
  unsigned short* q_b  = (unsigned short*)(ws + 132 * MB);  // 8 MB
  unsigned short* k_b  = (unsigned short*)(ws + 140 * MB);  // 2 MB
  unsigned short* vt_b = (unsigned short*)(ws + 142 * MB);  // 2 MB
  unsigned short* y_b  = (unsigned short*)(ws + 144 * MB);  // 8 MB
  unsigned short* wd_t = (unsigned short*)(ws + 132 * MB);  // 32 MB (after attn)

  // 1. Weight cast+transpose (wd deferred until attn scratch is dead).
  transpose_cast<<<dim3(64, 64), 256, 0, stream>>>(wq, wq_t, Dm, Dm);
  transpose_cast<<<dim3(16, 64), 256, 0, stream>>>(wk, wk_t, Dm, 512);
  transpose_cast<<<dim3(16, 64), 256, 0, stream>>>(wv, wv_t, Dm, 512);
  transpose_cast<<<dim3(64, 64), 256, 0, stream>>>(wo, wo_t, Dm, Dm);
  transpose_cast<<<dim3(256, 64), 256, 0, stream>>>(wg, wg_t, Dm, FF);
  transpose_cast<<<dim3(256, 64), 256, 0, stream>>>(wu, wu_t, Dm, FF);

  // 2. h1 = rms(x0)
  rmsnorm<<<T, 256, 0, stream>>>(x, g1, h1_b);

  // 3. Fused QKV projection (N=3072): rope q -> q_b, rope k -> k_b,
  //    transposed v -> vt_b.
  gemm_bt<<<dim3(24, 16), 256, 0, stream>>>(h1_b, wq_t, nullptr, q_b, nullptr,
                                            nullptr, 3072, Dm, Dm, 7, T, k_b,
                                            vt_b);

  // 4. Attention: 64 q-tiles x 32 heads, 4 independent waves/block.
  flash_attn<<<dim3(16, 32), 256, 0, stream>>>(q_b, k_b, vt_b, y_b, T);

  // 5. x2 = h1 + y @ wo  (epi 1).
  gemm_bt<<<dim3(16, 16), 256, 0, stream>>>(y_b, wo_t, x2_f, nullptr, h1_b,
                                            nullptr, Dm, Dm, Dm, 1, 0, nullptr,
                                            nullptr);

  // 6. wd transpose into the now-dead attention scratch.
  transpose_cast<<<dim3(64, 256), 256, 0, stream>>>(wd, wd_t, FF, Dm);

  // 7. h2 = rms(x2)
  rmsnorm<<<T, 256, 0, stream>>>(x2_f, g2, h2_b);

  // 8. MLP: gate (epi 4), then up fused with silu in-place (epi 3).
  gemm_bt<<<dim3(64, 16), 256, 0, stream>>>(h2_b, wg_t, nullptr, gate, nullptr,
                                            nullptr, FF, Dm, Dm, 4, 0, nullptr,
                                            nullptr);
  gemm_bt<<<dim3(64, 16), 256, 0, stream>>>(h2_b, wu_t, nullptr, gate, gate,
                                            nullptr, FF, Dm, Dm, 3, 0, nullptr,
                                            nullptr);

  // 9. out = h2 + x0 (pre-fill), then split-K x4 down-proj atomicAdd.
  add_res<<<(T * Dm / 4) / 256, 256, 0, stream>>>(h2_b, x, out);
  gemm_bt<<<dim3(16, 16, 4), 256, 0, stream>>>(gate, wd_t, out, nullptr,
                                               nullptr, nullptr, Dm, FF,
                                               FF / 4, 8, 0, nullptr, nullptr);
}